// Round 21
// baseline (72.325 us; speedup 1.0000x reference)
//
#include <hip/hip_runtime.h>

typedef unsigned char u8;
typedef signed char i8;
typedef unsigned int u32;
typedef __attribute__((ext_vector_type(4))) int i32x4;

#define AS1 __attribute__((address_space(1)))
#define AS3 __attribute__((address_space(3)))

__device__ __forceinline__ void gload_lds16(const void* g, void* l) {
    __builtin_amdgcn_global_load_lds((const AS1 void*)g, (AS3 void*)l, 16, 0, 0);
}

// ---------- merged prep: quant (blocks 0..3071) + transpose (blocks 3072+) ---
__global__ void prep(const float* __restrict__ X, i8* __restrict__ Xb,
                     const float4* __restrict__ W1, const float4* __restrict__ W2,
                     char4* __restrict__ W1q, char4* __restrict__ W2q) {
    const int n1v = 2048 * 1024 / 4, n2v = 512 * 2048 / 4;
    __shared__ float tile[128][33];
    int bid = blockIdx.x;
    if (bid < 3072) {                         // ---- quant branch
        int i = bid * 256 + threadIdx.x;
        if (i < n1v) {
            float4 w = W1[i];
            char4 q;
            q.x = (i8)(int)rintf(w.x * 0.5f);
            q.y = (i8)(int)rintf(w.y * 0.5f);
            q.z = (i8)(int)rintf(w.z * 0.5f);
            q.w = (i8)(int)rintf(w.w * 0.5f);
            W1q[i] = q;
        } else {
            int j = i - n1v;
            if (j < n2v) {
                float4 w = W2[j];
                char4 q;
                q.x = (i8)(int)rintf(w.x * 0.5f);
                q.y = (i8)(int)rintf(w.y * 0.5f);
                q.z = (i8)(int)rintf(w.z * 0.5f);
                q.w = (i8)(int)rintf(w.w * 0.5f);
                W2q[j] = q;
            }
        }
        return;
    }
    bid -= 3072;
    const int B = 32, IN = 1024, T = 256;
    const int t0 = (bid & 7) * 32, i0 = ((bid >> 3) & 7) * 128, b = bid >> 6;
    const int tx = threadIdx.x & 31, ty = threadIdx.x >> 5;
    const float* src = X + (size_t)b * IN * T;
#pragma unroll
    for (int r = 0; r < 16; ++r) {
        int i = ty + r * 8;
        tile[i][tx] = src[(size_t)(i0 + i) * T + t0 + tx];
    }
    __syncthreads();
    const int cx = threadIdx.x & 31;
    const int tl0 = threadIdx.x >> 5;
#pragma unroll
    for (int r = 0; r < 4; ++r) {
        int tl = tl0 + r * 8;
        uchar4 pk;
        pk.x = (tile[cx * 4 + 0][tl] != 0.f) ? 1 : 0;
        pk.y = (tile[cx * 4 + 1][tl] != 0.f) ? 1 : 0;
        pk.z = (tile[cx * 4 + 2][tl] != 0.f) ? 1 : 0;
        pk.w = (tile[cx * 4 + 3][tl] != 0.f) ? 1 : 0;
        *(uchar4*)&Xb[((size_t)b * T + t0 + tl) * IN + i0 + cx * 4] = pk;
    }
}

// ---------- FUSED GEMM1 + scan1, v7: 1024 thr -> 32 waves/CU (100% occ) ------
// 256x128 tile, 16 waves (4 wm x 4 wn of 64r x 32c), acc[4][2]. Same serial
// BK=128 2-barrier K-loop + both-sides XOR swizzle as R15 (schedule variants
// all proved neutral; occupancy is the isolated variable this round).
// LDS 69632 -> 2 blocks/CU x 1024 thr = 2048 thr/CU = 32 waves (100%).
// af read per-mf inside the MFMA loop to keep VGPR under the 8-wave budget.
__global__ __launch_bounds__(1024, 2) void gemm1_scan1(
        const i8* __restrict__ A, const i8* __restrict__ Bt,
        i8* __restrict__ S1, int K) {
    __shared__ __align__(16) i8 lds[69632];
    i8*    lA   = lds;                        // 256x128 staging (32 KB)
    i8*    lB   = lds + 32768;                // 128x128 staging (16 KB)
    short* hT   = (short*)lds;                // [128 n][256 t] i16 (alias, 64 KB)
    u32*   bits = (u32*)(lds + 65536);        // [8][128] u32 = 4 KB

    const int nwg = gridDim.x;                // 512, %8==0
    const int cpx = nwg >> 3;
    const int wg  = (blockIdx.x & 7) * cpx + (blockIdx.x >> 3);
    const int bx = wg & 15;                   // 16 neuron tiles of 128
    const int by = wg >> 4;                   // 32 batches
    const int n0 = bx * 128;
    const int m0 = by * 256;

    const int tid  = threadIdx.x;
    const int lane = tid & 63;
    const int w    = tid >> 6;                // 0..15
    const int wm   = w & 3;                   // M-quadrant (64 rows)
    const int wn   = w >> 2;                  // N-strip (32 cols)
    const int l15 = lane & 15;
    const int l4  = lane >> 4;
    const int sw  = l15 & 7;

    i32x4 acc[4][2] = {};
    const int flatT = tid * 16;

    for (int k0 = 0; k0 < K; k0 += 128) {     // 8 K-steps
        __syncthreads();
#pragma unroll
        for (int q = 0; q < 2; ++q) {         // A: 32 KB over 1024 thr
            int fl = q * 16384 + flatT;
            int r  = fl >> 7;
            int sc = ((fl >> 4) & 7) ^ (r & 7);
            gload_lds16(A + (size_t)(m0 + r) * K + k0 + sc * 16, &lA[fl]);
        }
        {                                     // B: 16 KB (128 rows x 128 B)
            int fl = flatT;
            int r  = fl >> 7;
            int sc = ((fl >> 4) & 7) ^ (r & 7);
            gload_lds16(Bt + (size_t)(n0 + r) * K + k0 + sc * 16, &lB[fl]);
        }
        __syncthreads();
#pragma unroll
        for (int kk = 0; kk < 2; ++kk) {
            const int co = ((kk * 4 + l4) ^ sw) * 16;
            i32x4 bf[2];
#pragma unroll
            for (int nf = 0; nf < 2; ++nf)
                bf[nf] = *(const i32x4*)&lB[(wn * 32 + nf * 16 + l15) * 128 + co];
#pragma unroll
            for (int mf = 0; mf < 4; ++mf) {
                i32x4 af = *(const i32x4*)&lA[(wm * 64 + mf * 16 + l15) * 128 + co];
                acc[mf][0] = __builtin_amdgcn_mfma_i32_16x16x64_i8(
                    af, bf[0], acc[mf][0], 0, 0, 0);
                acc[mf][1] = __builtin_amdgcn_mfma_i32_16x16x64_i8(
                    af, bf[1], acc[mf][1], 0, 0, 0);
            }
        }
    }
    __syncthreads();                          // staging LDS dead; reuse as hT

    // ---- phase 2: acc -> hT[n][t] i16, swizzled 8B (4-t) chunk writes -------
#pragma unroll
    for (int mf = 0; mf < 4; ++mf)
#pragma unroll
        for (int nf = 0; nf < 2; ++nf) {
            int n = wn * 32 + nf * 16 + l15;  // 0..127
            int c = wm * 16 + mf * 4 + l4;    // t-chunk 0..63
            int h0 = acc[mf][nf][0] * 2, h1 = acc[mf][nf][1] * 2;
            int h2 = acc[mf][nf][2] * 2, h3 = acc[mf][nf][3] * 2;
            int2 pk;
            pk.x = (h0 & 0xffff) | (h1 << 16);
            pk.y = (h2 & 0xffff) | (h3 << 16);
            *(int2*)((char*)hT + n * 512 + ((c ^ (n & 15)) << 3)) = pk;
        }
    __syncthreads();

    // ---- phase 3: two waves scan (64 neurons each, distinct SIMDs) ----------
    {
        const int ssel = blockIdx.x & 3;
        const int w1   = 4 + ((ssel + 1) & 3);
        const int nbase = (w == ssel) ? 0 : (w == w1) ? 64 : -1;
        if (nbase >= 0) {
            const int n = nbase + lane;
            const int nx = n & 15;
            const char* hrow = (char*)hT + n * 512;
            int2 ra[4], rb[4];
#pragma unroll
            for (int q = 0; q < 4; ++q)
                ra[q] = *(const int2*)(hrow + ((q ^ nx) << 3));
            u32 bw[8] = {0, 0, 0, 0, 0, 0, 0, 0};
            float I = 0.f, V = 0.f;
#pragma unroll
            for (int p = 0; p < 16; ++p) {
                if (p < 15) {
#pragma unroll
                    for (int q = 0; q < 4; ++q) {
                        int2 v = *(const int2*)(hrow + ((((p + 1) * 4 + q) ^ nx) << 3));
                        if (p & 1) ra[q] = v; else rb[q] = v;
                    }
                }
#pragma unroll
                for (int q = 0; q < 4; ++q) {
                    int2 hh = (p & 1) ? rb[q] : ra[q];
#pragma unroll
                    for (int j = 0; j < 4; ++j) {
                        int t = p * 16 + q * 4 + j;
                        short hv = (j == 0) ? (short)hh.x
                                 : (j == 1) ? (short)(hh.x >> 16)
                                 : (j == 2) ? (short)hh.y
                                            : (short)(hh.y >> 16);
                        I = floorf(I * 0.75f) + 64.f * (float)hv;
                        V = floorf(V * 0.96875f) + I;
                        if (V >= 5120.f) { bw[t >> 5] |= (1u << (t & 31)); V = 0.f; }
                    }
                }
            }
#pragma unroll
            for (int wi = 0; wi < 8; ++wi) bits[wi * 128 + n] = bw[wi];
        }
    }
    __syncthreads();

    // ---- phase 4: delay-shifted spike write, coalesced dwords ---------------
#pragma unroll
    for (int rep = 0; rep < 8; ++rep) {
        int d   = rep * 1024 + tid;           // 0..8191 = 256 rows x 32 dwords
        int tt  = d >> 5;
        int ndq = d & 31;
        u32 outw = 0;
        if (tt > 0) {
            int tb = tt - 1, wi = tb >> 5, sh = tb & 31;
            outw =  ((bits[wi * 128 + ndq * 4 + 0] >> sh) & 1)
                 | (((bits[wi * 128 + ndq * 4 + 1] >> sh) & 1) << 8)
                 | (((bits[wi * 128 + ndq * 4 + 2] >> sh) & 1) << 16)
                 | (((bits[wi * 128 + ndq * 4 + 3] >> sh) & 1) << 24);
        }
        *(u32*)&S1[(size_t)(m0 + tt) * 2048 + n0 + ndq * 4] = outw;
    }
}

// ---------- FUSED GEMM2 + scan2 + out-transpose (R19 v5, verbatim) -----------
__global__ __launch_bounds__(512, 2) void gemm2_scan2(
        const i8* __restrict__ A, const i8* __restrict__ Bt,
        float* __restrict__ out) {
    const int K = 2048;
    __shared__ __align__(16) i8 lds[81920];
    float* hT   = (float*)lds;                // [64 n][256 t] f32 (alias)
    u32*   bits = (u32*)(lds + 65536);        // [8][64] u32 = 2 KB (alias)

    const int nwg = gridDim.x;                // 256, %8==0
    const int cpx = nwg >> 3;
    const int wg  = (blockIdx.x & 7) * cpx + (blockIdx.x >> 3);
    const int scanw = blockIdx.x & 7;
    const int ox = wg & 7;                    // 8 o-tiles of 64
    const int by = wg >> 3;                   // 32 batches
    const int n0 = ox * 64;
    const int m0 = by * 256;

    const int tid  = threadIdx.x;
    const int lane = tid & 63;
    const int w    = tid >> 6;                // 0..7
    const int wm   = w & 3;                   // t-quadrant (64 rows)
    const int wn   = w >> 2;                  // o-half (32 cols)
    const int l15 = lane & 15;
    const int l4  = lane >> 4;
    const int sw  = l15 & 7;

    i32x4 acc[4][2] = {};

    auto STAGE = [&](int buf, int k0) {
        i8* lA = lds + buf * 40960;
        i8* lB = lA + 32768;
#pragma unroll
        for (int q = 0; q < 4; ++q) {         // A: 32 KB over 512 thr
            int fl = q * 8192 + tid * 16;
            int r  = fl >> 7;
            int sc = ((fl >> 4) & 7) ^ (r & 7);
            gload_lds16(A + (size_t)(m0 + r) * K + k0 + sc * 16, &lA[fl]);
        }
        {                                     // B: 8 KB (64 rows x 128)
            int fl = tid * 16;
            int r  = fl >> 7;
            int sc = ((fl >> 4) & 7) ^ (r & 7);
            gload_lds16(Bt + (size_t)(n0 + r) * K + k0 + sc * 16, &lB[fl]);
        }
    };

    auto COMPUTE = [&](int buf) {
        const i8* lA = lds + buf * 40960;
        const i8* lB = lA + 32768;
#pragma unroll
        for (int kk = 0; kk < 2; ++kk) {
            i32x4 af[4], bf[2];
#pragma unroll
            for (int mf = 0; mf < 4; ++mf)
                af[mf] = *(const i32x4*)&lA[(wm * 64 + mf * 16 + l15) * 128 +
                                            ((kk * 4 + l4) ^ sw) * 16];
#pragma unroll
            for (int nf = 0; nf < 2; ++nf)
                bf[nf] = *(const i32x4*)&lB[(wn * 32 + nf * 16 + l15) * 128 +
                                            ((kk * 4 + l4) ^ sw) * 16];
#pragma unroll
            for (int mf = 0; mf < 4; ++mf)
#pragma unroll
                for (int nf = 0; nf < 2; ++nf)
                    acc[mf][nf] = __builtin_amdgcn_mfma_i32_16x16x64_i8(
                        af[mf], bf[nf], acc[mf][nf], 0, 0, 0);
        }
    };

    STAGE(0, 0);
    __syncthreads();
    int cur = 0;
    for (int k0 = 0; k0 < K; k0 += 128) {     // 16 K-steps
        if (k0 + 128 < K) STAGE(cur ^ 1, k0 + 128);
        COMPUTE(cur);
        __syncthreads();
        cur ^= 1;
    }

    // ---- phase 2: acc*2 -> hT[n][t] f32, swizzled 16B (4-t) chunks ----------
#pragma unroll
    for (int mf = 0; mf < 4; ++mf)
#pragma unroll
        for (int nf = 0; nf < 2; ++nf) {
            int n = wn * 32 + nf * 16 + l15;  // 0..63
            int c = wm * 16 + mf * 4 + l4;    // t-chunk 0..63
            float4 pk;
            pk.x = (float)(acc[mf][nf][0] * 2);
            pk.y = (float)(acc[mf][nf][1] * 2);
            pk.z = (float)(acc[mf][nf][2] * 2);
            pk.w = (float)(acc[mf][nf][3] * 2);
            *(float4*)((char*)hT + n * 1024 + ((c ^ (n & 15)) << 4)) = pk;
        }
    __syncthreads();

    // ---- phase 3: one wave scans 64 neurons ---------------------------------
    if (w == scanw) {
        const int n = lane;
        const int nx = n & 15;
        const char* hrow = (char*)hT + n * 1024;
        float4 ra[4], rb[4];
#pragma unroll
        for (int q = 0; q < 4; ++q)
            ra[q] = *(const float4*)(hrow + ((q ^ nx) << 4));
        u32 bw[8] = {0, 0, 0, 0, 0, 0, 0, 0};
        float I = 0.f, V = 0.f;
#pragma unroll
        for (int p = 0; p < 16; ++p) {        // 16 phases x 16 t
            if (p < 15) {
#pragma unroll
                for (int q = 0; q < 4; ++q) {
                    float4 v = *(const float4*)(hrow + ((((p + 1) * 4 + q) ^ nx) << 4));
                    if (p & 1) ra[q] = v; else rb[q] = v;
                }
            }
#pragma unroll
            for (int q = 0; q < 4; ++q) {
                float4 hh = (p & 1) ? rb[q] : ra[q];
#pragma unroll
                for (int j = 0; j < 4; ++j) {
                    int t = p * 16 + q * 4 + j;
                    float hv = (j == 0) ? hh.x : (j == 1) ? hh.y
                             : (j == 2) ? hh.z : hh.w;
                    I = floorf(I * 0.75f) + 64.f * hv;
                    V = floorf(V * 0.96875f) + I;
                    if (V >= 5120.f) { bw[t >> 5] |= (1u << (t & 31)); V = 0.f; }
                }
            }
        }
#pragma unroll
        for (int wi = 0; wi < 8; ++wi) bits[wi * 64 + n] = bw[wi];
    }
    __syncthreads();

    // ---- phase 4: delay-shifted f32 spikes to out[b][o][t], coalesced -------
#pragma unroll
    for (int rep = 0; rep < 8; ++rep) {
        int flat = rep * 512 + tid;           // 0..4095 = 64 o x 64 t-quads
        int o  = flat >> 6;
        int t4 = flat & 63;
        float4 v;
#pragma unroll
        for (int j = 0; j < 4; ++j) {
            int tt = t4 * 4 + j;
            float s = 0.f;
            if (tt > 0) {
                int tb = tt - 1;
                s = (float)((bits[(tb >> 5) * 64 + o] >> (tb & 31)) & 1);
            }
            if (j == 0) v.x = s; else if (j == 1) v.y = s;
            else if (j == 2) v.z = s; else v.w = s;
        }
        *(float4*)&out[((size_t)by * 512 + n0 + o) * 256 + t4 * 4] = v;
    }
}

extern "C" void kernel_launch(void* const* d_in, const int* in_sizes, int n_in,
                              void* d_out, int out_size, void* d_ws, size_t ws_size,
                              hipStream_t stream) {
    const int B = 32, IN = 1024, HID = 2048, OUT = 512, T = 256;
    const float* spikes = (const float*)d_in[0];
    const float* W1 = (const float*)d_in[1];
    const float* W2 = (const float*)d_in[2];
    float* out = (float*)d_out;

    char* ws = (char*)d_ws;
    size_t off = 0;
    auto alloc = [&](size_t bytes) -> void* {
        void* p = ws + off;
        off += (bytes + 255) & ~(size_t)255;
        return p;
    };
    i8* Xb  = (i8*)alloc((size_t)B * T * IN);      // [B,T,IN] i8 0/1
    i8* W1q = (i8*)alloc((size_t)HID * IN);        // [HID,IN] i8 = w/2
    i8* W2q = (i8*)alloc((size_t)OUT * HID);       // [OUT,HID] i8 = w/2
    i8* S1  = (i8*)alloc((size_t)B * T * HID);     // [B,T,HID] i8 (shifted)

    prep<<<dim3(5120), dim3(256), 0, stream>>>(
        spikes, Xb, (const float4*)W1, (const float4*)W2,
        (char4*)W1q, (char4*)W2q);
    gemm1_scan1<<<dim3(512), dim3(1024), 0, stream>>>(Xb, W1q, S1, IN);
    gemm2_scan2<<<dim3(256), dim3(512), 0, stream>>>(S1, W2q, out);
}

// Round 22
// 71.814 us; speedup vs baseline: 1.0071x; 1.0071x over previous
//
#include <hip/hip_runtime.h>

typedef unsigned char u8;
typedef signed char i8;
typedef unsigned int u32;
typedef __attribute__((ext_vector_type(4))) int i32x4;

#define AS1 __attribute__((address_space(1)))
#define AS3 __attribute__((address_space(3)))

__device__ __forceinline__ void gload_lds16(const void* g, void* l) {
    __builtin_amdgcn_global_load_lds((const AS1 void*)g, (AS3 void*)l, 16, 0, 0);
}

// ---------- merged prep: quant (blocks 0..3071) + transpose (blocks 3072+) ---
__global__ void prep(const float* __restrict__ X, i8* __restrict__ Xb,
                     const float4* __restrict__ W1, const float4* __restrict__ W2,
                     char4* __restrict__ W1q, char4* __restrict__ W2q) {
    const int n1v = 2048 * 1024 / 4, n2v = 512 * 2048 / 4;
    __shared__ float tile[128][33];
    int bid = blockIdx.x;
    if (bid < 3072) {                         // ---- quant branch
        int i = bid * 256 + threadIdx.x;
        if (i < n1v) {
            float4 w = W1[i];
            char4 q;
            q.x = (i8)(int)rintf(w.x * 0.5f);
            q.y = (i8)(int)rintf(w.y * 0.5f);
            q.z = (i8)(int)rintf(w.z * 0.5f);
            q.w = (i8)(int)rintf(w.w * 0.5f);
            W1q[i] = q;
        } else {
            int j = i - n1v;
            if (j < n2v) {
                float4 w = W2[j];
                char4 q;
                q.x = (i8)(int)rintf(w.x * 0.5f);
                q.y = (i8)(int)rintf(w.y * 0.5f);
                q.z = (i8)(int)rintf(w.z * 0.5f);
                q.w = (i8)(int)rintf(w.w * 0.5f);
                W2q[j] = q;
            }
        }
        return;
    }
    bid -= 3072;
    const int B = 32, IN = 1024, T = 256;
    const int t0 = (bid & 7) * 32, i0 = ((bid >> 3) & 7) * 128, b = bid >> 6;
    const int tx = threadIdx.x & 31, ty = threadIdx.x >> 5;
    const float* src = X + (size_t)b * IN * T;
#pragma unroll
    for (int r = 0; r < 16; ++r) {
        int i = ty + r * 8;
        tile[i][tx] = src[(size_t)(i0 + i) * T + t0 + tx];
    }
    __syncthreads();
    const int cx = threadIdx.x & 31;
    const int tl0 = threadIdx.x >> 5;
#pragma unroll
    for (int r = 0; r < 4; ++r) {
        int tl = tl0 + r * 8;
        uchar4 pk;
        pk.x = (tile[cx * 4 + 0][tl] != 0.f) ? 1 : 0;
        pk.y = (tile[cx * 4 + 1][tl] != 0.f) ? 1 : 0;
        pk.z = (tile[cx * 4 + 2][tl] != 0.f) ? 1 : 0;
        pk.w = (tile[cx * 4 + 3][tl] != 0.f) ? 1 : 0;
        *(uchar4*)&Xb[((size_t)b * T + t0 + tl) * IN + i0 + cx * 4] = pk;
    }
}

// ---------- FUSED GEMM1 + scan1 (R15 K-loop; early-retire epilogue) ----------
// After the phase-2 barrier (last barrier, all waves), 6 of 8 waves RETURN.
// The 2 scan waves run phase 3 + phase 4 alone (own-wave data only), so the
// co-resident block's K-loop gets the freed SIMD issue slots during the tail.
__global__ __launch_bounds__(512, 4) void gemm1_scan1(
        const i8* __restrict__ A, const i8* __restrict__ Bt,
        i8* __restrict__ S1, int K) {
    __shared__ __align__(16) i8 lds[69632];
    i8*    lA   = lds;                        // 256x128 staging (32 KB)
    i8*    lB   = lds + 32768;                // 128x128 staging (16 KB)
    short* hT   = (short*)lds;                // [128 n][256 t] i16 (alias, 64 KB)
    u32*   bits = (u32*)(lds + 65536);        // [8][128] u32 = 4 KB

    const int nwg = gridDim.x;                // 512, %8==0
    const int cpx = nwg >> 3;
    const int wg  = (blockIdx.x & 7) * cpx + (blockIdx.x >> 3);
    const int bx = wg & 15;                   // 16 neuron tiles of 128
    const int by = wg >> 4;                   // 32 batches
    const int n0 = bx * 128;
    const int m0 = by * 256;

    const int tid  = threadIdx.x;
    const int lane = tid & 63;
    const int w    = tid >> 6;                // 0..7
    const int wm   = w & 3;                   // M-quadrant (64 rows)
    const int wn   = w >> 2;                  // N-half (64 cols)
    const int l15 = lane & 15;
    const int l4  = lane >> 4;
    const int sw  = l15 & 7;

    i32x4 acc[4][4] = {};
    const int flatT = tid * 16;

    for (int k0 = 0; k0 < K; k0 += 128) {     // 8 K-steps (R15-proven)
        __syncthreads();
#pragma unroll
        for (int q = 0; q < 4; ++q) {         // A: 32 KB over 512 thr
            int fl = q * 8192 + flatT;
            int r  = fl >> 7;
            int sc = ((fl >> 4) & 7) ^ (r & 7);
            gload_lds16(A + (size_t)(m0 + r) * K + k0 + sc * 16, &lA[fl]);
        }
#pragma unroll
        for (int q = 0; q < 2; ++q) {         // B: 16 KB
            int fl = q * 8192 + flatT;
            int r  = fl >> 7;
            int sc = ((fl >> 4) & 7) ^ (r & 7);
            gload_lds16(Bt + (size_t)(n0 + r) * K + k0 + sc * 16, &lB[fl]);
        }
        __syncthreads();
#pragma unroll
        for (int kk = 0; kk < 2; ++kk) {
            i32x4 af[4], bf[4];
#pragma unroll
            for (int mf = 0; mf < 4; ++mf)
                af[mf] = *(const i32x4*)&lA[(wm * 64 + mf * 16 + l15) * 128 +
                                            ((kk * 4 + l4) ^ sw) * 16];
#pragma unroll
            for (int nf = 0; nf < 4; ++nf)
                bf[nf] = *(const i32x4*)&lB[(wn * 64 + nf * 16 + l15) * 128 +
                                            ((kk * 4 + l4) ^ sw) * 16];
#pragma unroll
            for (int mf = 0; mf < 4; ++mf)
#pragma unroll
                for (int nf = 0; nf < 4; ++nf)
                    acc[mf][nf] = __builtin_amdgcn_mfma_i32_16x16x64_i8(
                        af[mf], bf[nf], acc[mf][nf], 0, 0, 0);
        }
    }
    __syncthreads();                          // staging LDS dead; reuse as hT

    // ---- phase 2: acc -> hT[n][t] i16, swizzled 8B (4-t) chunk writes -------
#pragma unroll
    for (int mf = 0; mf < 4; ++mf)
#pragma unroll
        for (int nf = 0; nf < 4; ++nf) {
            int n = wn * 64 + nf * 16 + l15;  // 0..127
            int c = wm * 16 + mf * 4 + l4;    // t-chunk 0..63
            int h0 = acc[mf][nf][0] * 2, h1 = acc[mf][nf][1] * 2;
            int h2 = acc[mf][nf][2] * 2, h3 = acc[mf][nf][3] * 2;
            int2 pk;
            pk.x = (h0 & 0xffff) | (h1 << 16);
            pk.y = (h2 & 0xffff) | (h3 << 16);
            *(int2*)((char*)hT + n * 512 + ((c ^ (n & 15)) << 3)) = pk;
        }
    __syncthreads();                          // LAST barrier (all waves)

    // ---- early retirement: non-scan waves free their SIMD slots -------------
    const int ssel = blockIdx.x & 3;
    const int w1   = 4 + ((ssel + 1) & 3);
    const int nbase = (w == ssel) ? 0 : (w == w1) ? 64 : -1;
    if (nbase < 0) return;

    // ---- phase 3: this wave scans its 64 neurons (hT complete at barrier) ---
    {
        const int n = nbase + lane;
        const int nx = n & 15;
        const char* hrow = (char*)hT + n * 512;
        int2 ra[4], rb[4];
#pragma unroll
        for (int q = 0; q < 4; ++q)
            ra[q] = *(const int2*)(hrow + ((q ^ nx) << 3));
        u32 bw[8] = {0, 0, 0, 0, 0, 0, 0, 0};
        float I = 0.f, V = 0.f;
#pragma unroll
        for (int p = 0; p < 16; ++p) {
            if (p < 15) {
#pragma unroll
                for (int q = 0; q < 4; ++q) {
                    int2 v = *(const int2*)(hrow + ((((p + 1) * 4 + q) ^ nx) << 3));
                    if (p & 1) ra[q] = v; else rb[q] = v;
                }
            }
#pragma unroll
            for (int q = 0; q < 4; ++q) {
                int2 hh = (p & 1) ? rb[q] : ra[q];
#pragma unroll
                for (int j = 0; j < 4; ++j) {
                    int t = p * 16 + q * 4 + j;
                    short hv = (j == 0) ? (short)hh.x
                             : (j == 1) ? (short)(hh.x >> 16)
                             : (j == 2) ? (short)hh.y
                                        : (short)(hh.y >> 16);
                    I = floorf(I * 0.75f) + 64.f * (float)hv;
                    V = floorf(V * 0.96875f) + I;
                    if (V >= 5120.f) { bw[t >> 5] |= (1u << (t & 31)); V = 0.f; }
                }
            }
        }
#pragma unroll
        for (int wi = 0; wi < 8; ++wi) bits[wi * 128 + nbase + lane] = bw[wi];
    }
    // same-wave LDS: no barrier needed (compiler orders via lgkmcnt)

    // ---- phase 4: this wave writes delay-shifted spikes for its 64 n --------
    for (int rep = 0; rep < 64; ++rep) {
        int d   = rep * 64 + lane;            // 0..4095 = 256 tt x 16 dwords
        int tt  = d >> 4;
        int nd4 = nbase + (d & 15) * 4;       // 4-neuron group within own 64
        u32 outw = 0;
        if (tt > 0) {
            int tb = tt - 1, wi = tb >> 5, sh = tb & 31;
            outw =  ((bits[wi * 128 + nd4 + 0] >> sh) & 1)
                 | (((bits[wi * 128 + nd4 + 1] >> sh) & 1) << 8)
                 | (((bits[wi * 128 + nd4 + 2] >> sh) & 1) << 16)
                 | (((bits[wi * 128 + nd4 + 3] >> sh) & 1) << 24);
        }
        *(u32*)&S1[(size_t)(m0 + tt) * 2048 + n0 + nd4] = outw;
    }
}

// ---------- FUSED GEMM2 + scan2 + out-transpose (R19 K-loop; early retire) ---
__global__ __launch_bounds__(512, 2) void gemm2_scan2(
        const i8* __restrict__ A, const i8* __restrict__ Bt,
        float* __restrict__ out) {
    const int K = 2048;
    __shared__ __align__(16) i8 lds[81920];
    float* hT   = (float*)lds;                // [64 n][256 t] f32 (alias)
    u32*   bits = (u32*)(lds + 65536);        // [8][64] u32 = 2 KB (alias)

    const int nwg = gridDim.x;                // 256, %8==0
    const int cpx = nwg >> 3;
    const int wg  = (blockIdx.x & 7) * cpx + (blockIdx.x >> 3);
    const int scanw = blockIdx.x & 7;
    const int ox = wg & 7;                    // 8 o-tiles of 64
    const int by = wg >> 3;                   // 32 batches
    const int n0 = ox * 64;
    const int m0 = by * 256;

    const int tid  = threadIdx.x;
    const int lane = tid & 63;
    const int w    = tid >> 6;                // 0..7
    const int wm   = w & 3;                   // t-quadrant (64 rows)
    const int wn   = w >> 2;                  // o-half (32 cols)
    const int l15 = lane & 15;
    const int l4  = lane >> 4;
    const int sw  = l15 & 7;

    i32x4 acc[4][2] = {};

    auto STAGE = [&](int buf, int k0) {
        i8* lA = lds + buf * 40960;
        i8* lB = lA + 32768;
#pragma unroll
        for (int q = 0; q < 4; ++q) {         // A: 32 KB over 512 thr
            int fl = q * 8192 + tid * 16;
            int r  = fl >> 7;
            int sc = ((fl >> 4) & 7) ^ (r & 7);
            gload_lds16(A + (size_t)(m0 + r) * K + k0 + sc * 16, &lA[fl]);
        }
        {                                     // B: 8 KB (64 rows x 128)
            int fl = tid * 16;
            int r  = fl >> 7;
            int sc = ((fl >> 4) & 7) ^ (r & 7);
            gload_lds16(Bt + (size_t)(n0 + r) * K + k0 + sc * 16, &lB[fl]);
        }
    };

    auto COMPUTE = [&](int buf) {
        const i8* lA = lds + buf * 40960;
        const i8* lB = lA + 32768;
#pragma unroll
        for (int kk = 0; kk < 2; ++kk) {
            i32x4 af[4], bf[2];
#pragma unroll
            for (int mf = 0; mf < 4; ++mf)
                af[mf] = *(const i32x4*)&lA[(wm * 64 + mf * 16 + l15) * 128 +
                                            ((kk * 4 + l4) ^ sw) * 16];
#pragma unroll
            for (int nf = 0; nf < 2; ++nf)
                bf[nf] = *(const i32x4*)&lB[(wn * 32 + nf * 16 + l15) * 128 +
                                            ((kk * 4 + l4) ^ sw) * 16];
#pragma unroll
            for (int mf = 0; mf < 4; ++mf)
#pragma unroll
                for (int nf = 0; nf < 2; ++nf)
                    acc[mf][nf] = __builtin_amdgcn_mfma_i32_16x16x64_i8(
                        af[mf], bf[nf], acc[mf][nf], 0, 0, 0);
        }
    };

    STAGE(0, 0);
    __syncthreads();
    int cur = 0;
    for (int k0 = 0; k0 < K; k0 += 128) {     // 16 K-steps
        if (k0 + 128 < K) STAGE(cur ^ 1, k0 + 128);
        COMPUTE(cur);
        __syncthreads();
        cur ^= 1;
    }

    // ---- phase 2: acc*2 -> hT[n][t] f32, swizzled 16B (4-t) chunks ----------
#pragma unroll
    for (int mf = 0; mf < 4; ++mf)
#pragma unroll
        for (int nf = 0; nf < 2; ++nf) {
            int n = wn * 32 + nf * 16 + l15;  // 0..63
            int c = wm * 16 + mf * 4 + l4;    // t-chunk 0..63
            float4 pk;
            pk.x = (float)(acc[mf][nf][0] * 2);
            pk.y = (float)(acc[mf][nf][1] * 2);
            pk.z = (float)(acc[mf][nf][2] * 2);
            pk.w = (float)(acc[mf][nf][3] * 2);
            *(float4*)((char*)hT + n * 1024 + ((c ^ (n & 15)) << 4)) = pk;
        }
    __syncthreads();                          // LAST barrier (all waves)

    // ---- early retirement: 7 of 8 waves exit --------------------------------
    if (w != scanw) return;

    // ---- phase 3: scan wave handles all 64 o --------------------------------
    {
        const int n = lane;
        const int nx = n & 15;
        const char* hrow = (char*)hT + n * 1024;
        float4 ra[4], rb[4];
#pragma unroll
        for (int q = 0; q < 4; ++q)
            ra[q] = *(const float4*)(hrow + ((q ^ nx) << 4));
        u32 bw[8] = {0, 0, 0, 0, 0, 0, 0, 0};
        float I = 0.f, V = 0.f;
#pragma unroll
        for (int p = 0; p < 16; ++p) {
            if (p < 15) {
#pragma unroll
                for (int q = 0; q < 4; ++q) {
                    float4 v = *(const float4*)(hrow + ((((p + 1) * 4 + q) ^ nx) << 4));
                    if (p & 1) ra[q] = v; else rb[q] = v;
                }
            }
#pragma unroll
            for (int q = 0; q < 4; ++q) {
                float4 hh = (p & 1) ? rb[q] : ra[q];
#pragma unroll
                for (int j = 0; j < 4; ++j) {
                    int t = p * 16 + q * 4 + j;
                    float hv = (j == 0) ? hh.x : (j == 1) ? hh.y
                             : (j == 2) ? hh.z : hh.w;
                    I = floorf(I * 0.75f) + 64.f * hv;
                    V = floorf(V * 0.96875f) + I;
                    if (V >= 5120.f) { bw[t >> 5] |= (1u << (t & 31)); V = 0.f; }
                }
            }
        }
#pragma unroll
        for (int wi = 0; wi < 8; ++wi) bits[wi * 64 + n] = bw[wi];
    }
    // same-wave LDS: no barrier needed

    // ---- phase 4: scan wave writes out[b][o][t] (delay-shifted) -------------
    for (int rep = 0; rep < 64; ++rep) {
        int d  = rep * 64 + lane;             // 0..4095 = 64 o x 64 t-quads
        int o  = d >> 6;
        int t4 = d & 63;
        float4 v;
#pragma unroll
        for (int j = 0; j < 4; ++j) {
            int tt = t4 * 4 + j;
            float s = 0.f;
            if (tt > 0) {
                int tb = tt - 1;
                s = (float)((bits[(tb >> 5) * 64 + o] >> (tb & 31)) & 1);
            }
            if (j == 0) v.x = s; else if (j == 1) v.y = s;
            else if (j == 2) v.z = s; else v.w = s;
        }
        *(float4*)&out[((size_t)by * 512 + n0 + o) * 256 + t4 * 4] = v;
    }
}

extern "C" void kernel_launch(void* const* d_in, const int* in_sizes, int n_in,
                              void* d_out, int out_size, void* d_ws, size_t ws_size,
                              hipStream_t stream) {
    const int B = 32, IN = 1024, HID = 2048, OUT = 512, T = 256;
    const float* spikes = (const float*)d_in[0];
    const float* W1 = (const float*)d_in[1];
    const float* W2 = (const float*)d_in[2];
    float* out = (float*)d_out;

    char* ws = (char*)d_ws;
    size_t off = 0;
    auto alloc = [&](size_t bytes) -> void* {
        void* p = ws + off;
        off += (bytes + 255) & ~(size_t)255;
        return p;
    };
    i8* Xb  = (i8*)alloc((size_t)B * T * IN);      // [B,T,IN] i8 0/1
    i8* W1q = (i8*)alloc((size_t)HID * IN);        // [HID,IN] i8 = w/2
    i8* W2q = (i8*)alloc((size_t)OUT * HID);       // [OUT,HID] i8 = w/2
    i8* S1  = (i8*)alloc((size_t)B * T * HID);     // [B,T,HID] i8 (shifted)

    prep<<<dim3(5120), dim3(256), 0, stream>>>(
        spikes, Xb, (const float4*)W1, (const float4*)W2,
        (char4*)W1q, (char4*)W2q);
    gemm1_scan1<<<dim3(512), dim3(512), 0, stream>>>(Xb, W1q, S1, IN);
    gemm2_scan2<<<dim3(256), dim3(512), 0, stream>>>(S1, W2q, out);
}

// Round 23
// 62.157 us; speedup vs baseline: 1.1636x; 1.1554x over previous
//
#include <hip/hip_runtime.h>

typedef unsigned char u8;
typedef signed char i8;
typedef unsigned int u32;
typedef __attribute__((ext_vector_type(4))) int i32x4;

#define AS1 __attribute__((address_space(1)))
#define AS3 __attribute__((address_space(3)))

__device__ __forceinline__ void gload_lds16(const void* g, void* l) {
    __builtin_amdgcn_global_load_lds((const AS1 void*)g, (AS3 void*)l, 16, 0, 0);
}

// ---------- merged prep: quant (blocks 0..3071) + transpose (blocks 3072+) ---
__global__ void prep(const float* __restrict__ X, i8* __restrict__ Xb,
                     const float4* __restrict__ W1, const float4* __restrict__ W2,
                     char4* __restrict__ W1q, char4* __restrict__ W2q) {
    const int n1v = 2048 * 1024 / 4, n2v = 512 * 2048 / 4;
    __shared__ float tile[128][33];
    int bid = blockIdx.x;
    if (bid < 3072) {                         // ---- quant branch
        int i = bid * 256 + threadIdx.x;
        if (i < n1v) {
            float4 w = W1[i];
            char4 q;
            q.x = (i8)(int)rintf(w.x * 0.5f);
            q.y = (i8)(int)rintf(w.y * 0.5f);
            q.z = (i8)(int)rintf(w.z * 0.5f);
            q.w = (i8)(int)rintf(w.w * 0.5f);
            W1q[i] = q;
        } else {
            int j = i - n1v;
            if (j < n2v) {
                float4 w = W2[j];
                char4 q;
                q.x = (i8)(int)rintf(w.x * 0.5f);
                q.y = (i8)(int)rintf(w.y * 0.5f);
                q.z = (i8)(int)rintf(w.z * 0.5f);
                q.w = (i8)(int)rintf(w.w * 0.5f);
                W2q[j] = q;
            }
        }
        return;
    }
    bid -= 3072;
    const int B = 32, IN = 1024, T = 256;
    const int t0 = (bid & 7) * 32, i0 = ((bid >> 3) & 7) * 128, b = bid >> 6;
    const int tx = threadIdx.x & 31, ty = threadIdx.x >> 5;
    const float* src = X + (size_t)b * IN * T;
#pragma unroll
    for (int r = 0; r < 16; ++r) {
        int i = ty + r * 8;
        tile[i][tx] = src[(size_t)(i0 + i) * T + t0 + tx];
    }
    __syncthreads();
    const int cx = threadIdx.x & 31;
    const int tl0 = threadIdx.x >> 5;
#pragma unroll
    for (int r = 0; r < 4; ++r) {
        int tl = tl0 + r * 8;
        uchar4 pk;
        pk.x = (tile[cx * 4 + 0][tl] != 0.f) ? 1 : 0;
        pk.y = (tile[cx * 4 + 1][tl] != 0.f) ? 1 : 0;
        pk.z = (tile[cx * 4 + 2][tl] != 0.f) ? 1 : 0;
        pk.w = (tile[cx * 4 + 3][tl] != 0.f) ? 1 : 0;
        *(uchar4*)&Xb[((size_t)b * T + t0 + tl) * IN + i0 + cx * 4] = pk;
    }
}

// ---------- FUSED GEMM1 + Loihi scan1 (R15-best, verbatim) -------------------
__global__ __launch_bounds__(512, 4) void gemm1_scan1(
        const i8* __restrict__ A, const i8* __restrict__ Bt,
        i8* __restrict__ S1, int K) {
    __shared__ __align__(16) i8 lds[69632];
    i8*    lA   = lds;                        // 256x128 staging (32 KB)
    i8*    lB   = lds + 32768;                // 128x128 staging (16 KB)
    short* hT   = (short*)lds;                // [128 n][256 t] i16 (alias, 64 KB)
    u32*   bits = (u32*)(lds + 65536);        // [8][128] u32 = 4 KB

    const int nwg = gridDim.x;                // 512, %8==0
    const int cpx = nwg >> 3;
    const int wg  = (blockIdx.x & 7) * cpx + (blockIdx.x >> 3);
    const int bx = wg & 15;                   // 16 neuron tiles of 128
    const int by = wg >> 4;                   // 32 batches
    const int n0 = bx * 128;
    const int m0 = by * 256;

    const int tid  = threadIdx.x;
    const int lane = tid & 63;
    const int w    = tid >> 6;                // 0..7
    const int wm   = w & 3;                   // M-quadrant (64 rows)
    const int wn   = w >> 2;                  // N-half (64 cols)
    const int l15 = lane & 15;
    const int l4  = lane >> 4;
    const int sw  = l15 & 7;

    i32x4 acc[4][4] = {};
    const int flatT = tid * 16;

    for (int k0 = 0; k0 < K; k0 += 128) {     // 8 K-steps
        __syncthreads();
#pragma unroll
        for (int q = 0; q < 4; ++q) {         // A: 32 KB over 512 thr
            int fl = q * 8192 + flatT;
            int r  = fl >> 7;
            int sc = ((fl >> 4) & 7) ^ (r & 7);
            gload_lds16(A + (size_t)(m0 + r) * K + k0 + sc * 16, &lA[fl]);
        }
#pragma unroll
        for (int q = 0; q < 2; ++q) {         // B: 16 KB
            int fl = q * 8192 + flatT;
            int r  = fl >> 7;
            int sc = ((fl >> 4) & 7) ^ (r & 7);
            gload_lds16(Bt + (size_t)(n0 + r) * K + k0 + sc * 16, &lB[fl]);
        }
        __syncthreads();
#pragma unroll
        for (int kk = 0; kk < 2; ++kk) {
            i32x4 af[4], bf[4];
#pragma unroll
            for (int mf = 0; mf < 4; ++mf)
                af[mf] = *(const i32x4*)&lA[(wm * 64 + mf * 16 + l15) * 128 +
                                            ((kk * 4 + l4) ^ sw) * 16];
#pragma unroll
            for (int nf = 0; nf < 4; ++nf)
                bf[nf] = *(const i32x4*)&lB[(wn * 64 + nf * 16 + l15) * 128 +
                                            ((kk * 4 + l4) ^ sw) * 16];
#pragma unroll
            for (int mf = 0; mf < 4; ++mf)
#pragma unroll
                for (int nf = 0; nf < 4; ++nf)
                    acc[mf][nf] = __builtin_amdgcn_mfma_i32_16x16x64_i8(
                        af[mf], bf[nf], acc[mf][nf], 0, 0, 0);
        }
    }
    __syncthreads();                          // staging LDS dead; reuse as hT

    // ---- phase 2: acc -> hT[n][t] i16, swizzled 8B (4-t) chunk writes -------
#pragma unroll
    for (int mf = 0; mf < 4; ++mf)
#pragma unroll
        for (int nf = 0; nf < 4; ++nf) {
            int n = wn * 64 + nf * 16 + l15;  // 0..127
            int c = wm * 16 + mf * 4 + l4;    // t-chunk 0..63
            int h0 = acc[mf][nf][0] * 2, h1 = acc[mf][nf][1] * 2;
            int h2 = acc[mf][nf][2] * 2, h3 = acc[mf][nf][3] * 2;
            int2 pk;
            pk.x = (h0 & 0xffff) | (h1 << 16);
            pk.y = (h2 & 0xffff) | (h3 << 16);
            *(int2*)((char*)hT + n * 512 + ((c ^ (n & 15)) << 3)) = pk;
        }
    __syncthreads();

    // ---- phase 3: two waves scan (64 neurons each) --------------------------
    {
        const int ssel = blockIdx.x & 3;
        const int w1   = 4 + ((ssel + 1) & 3);
        const int nbase = (w == ssel) ? 0 : (w == w1) ? 64 : -1;
        if (nbase >= 0) {
            const int n = nbase + lane;
            const int nx = n & 15;
            const char* hrow = (char*)hT + n * 512;
            int2 ra[4], rb[4];
#pragma unroll
            for (int q = 0; q < 4; ++q)
                ra[q] = *(const int2*)(hrow + ((q ^ nx) << 3));
            u32 bw[8] = {0, 0, 0, 0, 0, 0, 0, 0};
            float I = 0.f, V = 0.f;
#pragma unroll
            for (int p = 0; p < 16; ++p) {
                if (p < 15) {
#pragma unroll
                    for (int q = 0; q < 4; ++q) {
                        int2 v = *(const int2*)(hrow + ((((p + 1) * 4 + q) ^ nx) << 3));
                        if (p & 1) ra[q] = v; else rb[q] = v;
                    }
                }
#pragma unroll
                for (int q = 0; q < 4; ++q) {
                    int2 hh = (p & 1) ? rb[q] : ra[q];
#pragma unroll
                    for (int j = 0; j < 4; ++j) {
                        int t = p * 16 + q * 4 + j;
                        short hv = (j == 0) ? (short)hh.x
                                 : (j == 1) ? (short)(hh.x >> 16)
                                 : (j == 2) ? (short)hh.y
                                            : (short)(hh.y >> 16);
                        I = floorf(I * 0.75f) + 64.f * (float)hv;
                        V = floorf(V * 0.96875f) + I;
                        if (V >= 5120.f) { bw[t >> 5] |= (1u << (t & 31)); V = 0.f; }
                    }
                }
            }
#pragma unroll
            for (int wi = 0; wi < 8; ++wi) bits[wi * 128 + n] = bw[wi];
        }
    }
    __syncthreads();

    // ---- phase 4: delay-shifted spike write, coalesced dwords ---------------
#pragma unroll
    for (int rep = 0; rep < 16; ++rep) {
        int d   = rep * 512 + tid;            // 0..8191 = 256 rows x 32 dwords
        int tt  = d >> 5;
        int ndq = d & 31;
        u32 outw = 0;
        if (tt > 0) {
            int tb = tt - 1, wi = tb >> 5, sh = tb & 31;
            outw =  ((bits[wi * 128 + ndq * 4 + 0] >> sh) & 1)
                 | (((bits[wi * 128 + ndq * 4 + 1] >> sh) & 1) << 8)
                 | (((bits[wi * 128 + ndq * 4 + 2] >> sh) & 1) << 16)
                 | (((bits[wi * 128 + ndq * 4 + 3] >> sh) & 1) << 24);
        }
        *(u32*)&S1[(size_t)(m0 + tt) * 2048 + n0 + ndq * 4] = outw;
    }
}

// ---------- FUSED GEMM2 + scan2 + out-transpose (R19 v5, verbatim) -----------
__global__ __launch_bounds__(512, 2) void gemm2_scan2(
        const i8* __restrict__ A, const i8* __restrict__ Bt,
        float* __restrict__ out) {
    const int K = 2048;
    __shared__ __align__(16) i8 lds[81920];
    float* hT   = (float*)lds;                // [64 n][256 t] f32 (alias)
    u32*   bits = (u32*)(lds + 65536);        // [8][64] u32 = 2 KB (alias)

    const int nwg = gridDim.x;                // 256, %8==0
    const int cpx = nwg >> 3;
    const int wg  = (blockIdx.x & 7) * cpx + (blockIdx.x >> 3);
    const int scanw = blockIdx.x & 7;
    const int ox = wg & 7;                    // 8 o-tiles of 64
    const int by = wg >> 3;                   // 32 batches
    const int n0 = ox * 64;
    const int m0 = by * 256;

    const int tid  = threadIdx.x;
    const int lane = tid & 63;
    const int w    = tid >> 6;                // 0..7
    const int wm   = w & 3;                   // t-quadrant (64 rows)
    const int wn   = w >> 2;                  // o-half (32 cols)
    const int l15 = lane & 15;
    const int l4  = lane >> 4;
    const int sw  = l15 & 7;

    i32x4 acc[4][2] = {};

    auto STAGE = [&](int buf, int k0) {
        i8* lA = lds + buf * 40960;
        i8* lB = lA + 32768;
#pragma unroll
        for (int q = 0; q < 4; ++q) {         // A: 32 KB over 512 thr
            int fl = q * 8192 + tid * 16;
            int r  = fl >> 7;
            int sc = ((fl >> 4) & 7) ^ (r & 7);
            gload_lds16(A + (size_t)(m0 + r) * K + k0 + sc * 16, &lA[fl]);
        }
        {                                     // B: 8 KB (64 rows x 128)
            int fl = tid * 16;
            int r  = fl >> 7;
            int sc = ((fl >> 4) & 7) ^ (r & 7);
            gload_lds16(Bt + (size_t)(n0 + r) * K + k0 + sc * 16, &lB[fl]);
        }
    };

    auto COMPUTE = [&](int buf) {
        const i8* lA = lds + buf * 40960;
        const i8* lB = lA + 32768;
#pragma unroll
        for (int kk = 0; kk < 2; ++kk) {
            i32x4 af[4], bf[2];
#pragma unroll
            for (int mf = 0; mf < 4; ++mf)
                af[mf] = *(const i32x4*)&lA[(wm * 64 + mf * 16 + l15) * 128 +
                                            ((kk * 4 + l4) ^ sw) * 16];
#pragma unroll
            for (int nf = 0; nf < 2; ++nf)
                bf[nf] = *(const i32x4*)&lB[(wn * 32 + nf * 16 + l15) * 128 +
                                            ((kk * 4 + l4) ^ sw) * 16];
#pragma unroll
            for (int mf = 0; mf < 4; ++mf)
#pragma unroll
                for (int nf = 0; nf < 2; ++nf)
                    acc[mf][nf] = __builtin_amdgcn_mfma_i32_16x16x64_i8(
                        af[mf], bf[nf], acc[mf][nf], 0, 0, 0);
        }
    };

    STAGE(0, 0);
    __syncthreads();
    int cur = 0;
    for (int k0 = 0; k0 < K; k0 += 128) {     // 16 K-steps
        if (k0 + 128 < K) STAGE(cur ^ 1, k0 + 128);
        COMPUTE(cur);
        __syncthreads();
        cur ^= 1;
    }

    // ---- phase 2: acc*2 -> hT[n][t] f32, swizzled 16B (4-t) chunks ----------
#pragma unroll
    for (int mf = 0; mf < 4; ++mf)
#pragma unroll
        for (int nf = 0; nf < 2; ++nf) {
            int n = wn * 32 + nf * 16 + l15;  // 0..63
            int c = wm * 16 + mf * 4 + l4;    // t-chunk 0..63
            float4 pk;
            pk.x = (float)(acc[mf][nf][0] * 2);
            pk.y = (float)(acc[mf][nf][1] * 2);
            pk.z = (float)(acc[mf][nf][2] * 2);
            pk.w = (float)(acc[mf][nf][3] * 2);
            *(float4*)((char*)hT + n * 1024 + ((c ^ (n & 15)) << 4)) = pk;
        }
    __syncthreads();

    // ---- phase 3: one wave scans 64 neurons ---------------------------------
    if (w == scanw) {
        const int n = lane;
        const int nx = n & 15;
        const char* hrow = (char*)hT + n * 1024;
        float4 ra[4], rb[4];
#pragma unroll
        for (int q = 0; q < 4; ++q)
            ra[q] = *(const float4*)(hrow + ((q ^ nx) << 4));
        u32 bw[8] = {0, 0, 0, 0, 0, 0, 0, 0};
        float I = 0.f, V = 0.f;
#pragma unroll
        for (int p = 0; p < 16; ++p) {        // 16 phases x 16 t
            if (p < 15) {
#pragma unroll
                for (int q = 0; q < 4; ++q) {
                    float4 v = *(const float4*)(hrow + ((((p + 1) * 4 + q) ^ nx) << 4));
                    if (p & 1) ra[q] = v; else rb[q] = v;
                }
            }
#pragma unroll
            for (int q = 0; q < 4; ++q) {
                float4 hh = (p & 1) ? rb[q] : ra[q];
#pragma unroll
                for (int j = 0; j < 4; ++j) {
                    int t = p * 16 + q * 4 + j;
                    float hv = (j == 0) ? hh.x : (j == 1) ? hh.y
                             : (j == 2) ? hh.z : hh.w;
                    I = floorf(I * 0.75f) + 64.f * hv;
                    V = floorf(V * 0.96875f) + I;
                    if (V >= 5120.f) { bw[t >> 5] |= (1u << (t & 31)); V = 0.f; }
                }
            }
        }
#pragma unroll
        for (int wi = 0; wi < 8; ++wi) bits[wi * 64 + n] = bw[wi];
    }
    __syncthreads();

    // ---- phase 4: delay-shifted f32 spikes to out[b][o][t], coalesced -------
#pragma unroll
    for (int rep = 0; rep < 8; ++rep) {
        int flat = rep * 512 + tid;           // 0..4095 = 64 o x 64 t-quads
        int o  = flat >> 6;
        int t4 = flat & 63;
        float4 v;
#pragma unroll
        for (int j = 0; j < 4; ++j) {
            int tt = t4 * 4 + j;
            float s = 0.f;
            if (tt > 0) {
                int tb = tt - 1;
                s = (float)((bits[(tb >> 5) * 64 + o] >> (tb & 31)) & 1);
            }
            if (j == 0) v.x = s; else if (j == 1) v.y = s;
            else if (j == 2) v.z = s; else v.w = s;
        }
        *(float4*)&out[((size_t)by * 512 + n0 + o) * 256 + t4 * 4] = v;
    }
}

extern "C" void kernel_launch(void* const* d_in, const int* in_sizes, int n_in,
                              void* d_out, int out_size, void* d_ws, size_t ws_size,
                              hipStream_t stream) {
    const int B = 32, IN = 1024, HID = 2048, OUT = 512, T = 256;
    const float* spikes = (const float*)d_in[0];
    const float* W1 = (const float*)d_in[1];
    const float* W2 = (const float*)d_in[2];
    float* out = (float*)d_out;

    char* ws = (char*)d_ws;
    size_t off = 0;
    auto alloc = [&](size_t bytes) -> void* {
        void* p = ws + off;
        off += (bytes + 255) & ~(size_t)255;
        return p;
    };
    i8* Xb  = (i8*)alloc((size_t)B * T * IN);      // [B,T,IN] i8 0/1
    i8* W1q = (i8*)alloc((size_t)HID * IN);        // [HID,IN] i8 = w/2
    i8* W2q = (i8*)alloc((size_t)OUT * HID);       // [OUT,HID] i8 = w/2
    i8* S1  = (i8*)alloc((size_t)B * T * HID);     // [B,T,HID] i8 (shifted)

    prep<<<dim3(5120), dim3(256), 0, stream>>>(
        spikes, Xb, (const float4*)W1, (const float4*)W2,
        (char4*)W1q, (char4*)W2q);
    gemm1_scan1<<<dim3(512), dim3(512), 0, stream>>>(Xb, W1q, S1, IN);
    gemm2_scan2<<<dim3(256), dim3(512), 0, stream>>>(S1, W2q, out);
}